// Round 15
// baseline (132.582 us; speedup 1.0000x reference)
//
#include <hip/hip_runtime.h>

// Problem constants (fixed by setup_inputs)
constexpr int B = 4, N = 2048, I = 256, H = 4, D = 64, E = 256; // E = H*D
constexpr float LOG2E = 1.44269504088896340736f;

typedef __bf16 bf16x8 __attribute__((ext_vector_type(8)));
typedef float f32x4 __attribute__((ext_vector_type(4)));
typedef unsigned short us8 __attribute__((ext_vector_type(8)));

#if __has_builtin(__builtin_amdgcn_exp2f)
#define EXP2(x) __builtin_amdgcn_exp2f(x)
#else
#define EXP2(x) __expf((x) * 0.69314718055994530942f)
#endif

__device__ __forceinline__ unsigned short f2bf(float f) {
    unsigned u = __builtin_bit_cast(unsigned, f);
    u = (u + 0x7FFFu + ((u >> 16) & 1u)) >> 16;  // RNE
    return (unsigned short)u;
}
__device__ __forceinline__ float bf2f(unsigned short s) {
    return __builtin_bit_cast(float, (unsigned)s << 16);
}

constexpr int CH = 4096;       // u16 per (jqp,b,it) chunk: 64 q-slots x 64 lanes
constexpr int PROJ_BLKS = 256; // 512 row-tiles x 2 eh / 4 waves
constexpr int PACK_BLKS = B * N / 4;
constexpr int JQ = 4;          // partial chunks per i-tile

// ---------------- Kernel 0: weight conversions (must precede k_prep) ----------------
// blocks [0,32): Wo -> WoF hi/lo B-frag order: chunk (et*8+ks)*64+l, e = Wo[et*16+(l&15)][ks*32+(l>>4)*8+e]
// blocks [32,64): W -> WfF hi/lo B-frag order: e = Wf[ks*32+(l>>4)*8+e][et*16+(l&15)], Wf[k][c]=W[c>>6][k][c&63]
__global__ __launch_bounds__(256) void k_wconv(const float* __restrict__ Wo,
                                               const float* __restrict__ W,
                                               unsigned short* __restrict__ WoF,
                                               unsigned short* __restrict__ WfF) {
    int bid = blockIdx.x;
    int t = threadIdx.x;
    if (bid < 32) {
        int gid = bid * 256 + t;  // 8192
        int l = gid & 63, ks = (gid >> 6) & 7, et = gid >> 9;
        int row = et * 16 + (l & 15);
        int col = ks * 32 + (l >> 4) * 8;
        const float* src = Wo + (size_t)row * E + col;
        us8 hi, lo;
        #pragma unroll
        for (int e = 0; e < 8; ++e) {
            float v = src[e];
            unsigned short hb = f2bf(v);
            hi[e] = hb;
            lo[e] = f2bf(v - bf2f(hb));
        }
        ((us8*)WoF)[gid] = hi;
        ((us8*)WoF)[8192 + gid] = lo;
    } else {
        int gid = (bid - 32) * 256 + t;  // 8192
        int l = gid & 63, ks = (gid >> 6) & 7, et = gid >> 9;
        int c = et * 16 + (l & 15);
        int h = c >> 6, d = c & 63;
        int k0 = ks * 32 + (l >> 4) * 8;
        const float* src = W + ((size_t)h * I + k0) * D + d; // stride D per k
        us8 hi, lo;
        #pragma unroll
        for (int e = 0; e < 8; ++e) {
            float v = src[(size_t)e * D];
            unsigned short hb = f2bf(v);
            hi[e] = hb;
            lo[e] = f2bf(v - bf2f(hb));
        }
        ((us8*)WfF)[gid] = hi;
        ((us8*)WfF)[8192 + gid] = lo;
    }
}

// ---------------- Kernel 1 (fused prep): MFMA projection | adjacency pack ----------------
// proj blocks [0,256): wave-unit u = bid*4+wv; eh=u&1 (col half), rt=u>>1: b=rt>>7, n0=(rt&127)*16.
//   Hp tile [16 nodes x 128 cols] = X(hi/lo) @ WfF(hi/lo), 3 cross MFMAs, fp32 acc.
//   Epilogue: H1/H2 via in-reg dot + 16-lane shfl reduce; HpF via per-wave LDS transpose.
// pack blocks [256, 256+2048): one wave per (b,i) row; lane l builds Abits word jw=l
//   from 8 int4 loads (A values are {0,1} so the bit IS the value; no ballot chain).
__global__ __launch_bounds__(256) void k_prep(const float* __restrict__ X,
                                              const int* __restrict__ A,
                                              const float* __restrict__ a,
                                              const unsigned short* __restrict__ WfF,
                                              unsigned short* __restrict__ HpF,
                                              float* __restrict__ H1,
                                              float* __restrict__ H2i,
                                              unsigned int* __restrict__ Abits) {
    __shared__ float ldsT[4][16 * 132]; // per-wave transpose scratch, pad stride 132

    int bid = blockIdx.x;
    int t = threadIdx.x;

    if (bid < PROJ_BLKS) {
        int wv = t >> 6, l = t & 63;
        int u = bid * 4 + wv;
        int eh = u & 1;
        int rt = u >> 1;
        int b = rt >> 7;
        int n0 = (rt & 127) * 16;
        int m = l & 15;   // A-frag row
        int kh = l >> 4;  // k-chunk

        const float* Xrow = X + ((size_t)b * N + n0 + m) * I + kh * 8;
        const us8* wf = (const us8*)WfF;

        f32x4 acc[8] = {};

        #pragma unroll
        for (int ks = 0; ks < 8; ++ks) {
            float4 xa = *(const float4*)(Xrow + ks * 32);
            float4 xb = *(const float4*)(Xrow + ks * 32 + 4);
            float xv[8] = {xa.x, xa.y, xa.z, xa.w, xb.x, xb.y, xb.z, xb.w};
            bf16x8 xh, xl;
            #pragma unroll
            for (int e = 0; e < 8; ++e) {
                unsigned short hb = f2bf(xv[e]);
                xh[e] = __builtin_bit_cast(__bf16, hb);
                xl[e] = __builtin_bit_cast(__bf16, f2bf(xv[e] - bf2f(hb)));
            }
            #pragma unroll
            for (int etl = 0; etl < 8; ++etl) {
                int et = eh * 8 + etl;
                bf16x8 wh = __builtin_bit_cast(bf16x8, wf[(size_t)(et * 8 + ks) * 64 + l]);
                bf16x8 wl = __builtin_bit_cast(bf16x8, wf[8192 + (size_t)(et * 8 + ks) * 64 + l]);
                acc[etl] = __builtin_amdgcn_mfma_f32_16x16x32_bf16(xh, wh, acc[etl], 0, 0, 0);
                acc[etl] = __builtin_amdgcn_mfma_f32_16x16x32_bf16(xl, wh, acc[etl], 0, 0, 0);
                acc[etl] = __builtin_amdgcn_mfma_f32_16x16x32_bf16(xh, wl, acc[etl], 0, 0, 0);
            }
        }

        // ---- H1/H2: dot with a over d, reduce over the 16 C-cols ----
        float a1v[8], a2v[8];
        #pragma unroll
        for (int etl = 0; etl < 8; ++etl) {
            int c = eh * 128 + etl * 16 + m; // C col = l&15
            int h = c >> 6, d = c & 63;
            a1v[etl] = a[h * (2 * D) + d];
            a2v[etl] = a[h * (2 * D) + D + d];
        }
        #pragma unroll
        for (int hh = 0; hh < 2; ++hh) {
            #pragma unroll
            for (int r = 0; r < 4; ++r) {
                float s1 = 0.f, s2 = 0.f;
                #pragma unroll
                for (int q = 0; q < 4; ++q) {
                    s1 += acc[hh * 4 + q][r] * a1v[hh * 4 + q];
                    s2 += acc[hh * 4 + q][r] * a2v[hh * 4 + q];
                }
                #pragma unroll
                for (int off = 1; off < 16; off <<= 1) {
                    s1 += __shfl_xor(s1, off, 64);
                    s2 += __shfl_xor(s2, off, 64);
                }
                if (m == 0) {
                    int hg = eh * 2 + hh;
                    int row = kh * 4 + r; // C row
                    H1[(size_t)(b * H + hg) * N + n0 + row] = s1 * LOG2E;
                    H2i[((size_t)b * N + n0 + row) * H + hg] = s2 * LOG2E;
                }
            }
        }

        // ---- HpF: per-wave LDS transpose (same-wave, no barrier needed) ----
        float* lw = ldsT[wv];
        #pragma unroll
        for (int etl = 0; etl < 8; ++etl)
            #pragma unroll
            for (int r = 0; r < 4; ++r)
                lw[(kh * 4 + r) * 132 + etl * 16 + m] = acc[etl][r];

        #pragma unroll
        for (int cc = 0; cc < 4; ++cc) {
            int ci = cc * 64 + l;
            int c_local = ci >> 1, q = ci & 1;
            us8 o;
            #pragma unroll
            for (int e = 0; e < 8; ++e)
                o[e] = f2bf(lw[(q * 8 + e) * 132 + c_local]);
            int cg = eh * 128 + c_local;
            int h = cg >> 6, d = cg & 63;
            int nb = n0 + q * 8;
            int jblk = nb >> 5, g = (nb >> 3) & 3;
            ((us8*)HpF)[(((size_t)(b * H + h) * 64 + jblk) * 4 + (d >> 4)) * 64 + ((d & 15) + 16 * g)] = o;
        }

    } else {
        // ---------------- adjacency pack: per-lane word, no ballot ----------------
        int blk = bid - PROJ_BLKS;
        int w = blk * 4 + (t >> 6); // row id = b*N + i
        int l = t & 63;
        int b = w >> 11;
        int i = w & 2047;
        const int4* Arow = (const int4*)(A + (size_t)w * N) + l * 8; // lane covers j in [l*32, l*32+32)
        unsigned word = 0;
        #pragma unroll
        for (int c = 0; c < 8; ++c) {
            int4 v = Arow[c];
            word |= ((unsigned)v.x << (c * 4 + 0)) | ((unsigned)v.y << (c * 4 + 1)) |
                    ((unsigned)v.z << (c * 4 + 2)) | ((unsigned)v.w << (c * 4 + 3));
        }
        Abits[(size_t)b * 64 * 2048 + (size_t)l * 2048 + i] = word;
    }
}

// ---------------- Kernel 2: 2-i-tile-per-wave head-softmax + MFMA aggregation ----------------
// 512 blocks x 4 waves. Wave wv = (djq<<1)|dig: covers i-tiles itA=itp*4+dig*2, itB=itA+1
// (32 rows) and j-range jb=(jqp*2+djq)*256 (8 steps of 32 j). The 16 Hf B-frag loads per
// step now feed 32 MFMAs (2 A-frags) -> B-traffic per output halved vs 1-tile waves.
// XCD-locality: bid&7 fixes (b, jqp parity) -> L2-resident working set per XCD.
// Epilogue: djq=1 waves dump both tiles bf16 -> LDS; barrier; djq=0 add + write 2 chunks.
constexpr int NSTEP = 8;

__global__ __launch_bounds__(256) void k_agg(const unsigned int* __restrict__ Abits,
                                             const float* __restrict__ H1,
                                             const float* __restrict__ H2i,
                                             const unsigned short* __restrict__ HpF,
                                             unsigned short* __restrict__ part) {
    __shared__ unsigned short red[2][2][CH]; // 32 KB: [dig][tile][q*64+l]

    int bid = blockIdx.x;
    int x   = bid & 15;          // jqp*4 + b  (low bits -> XCD locality)
    int b   = x & 3;
    int jqp = x >> 2;            // 0..3
    int itp = bid >> 4;          // 0..31
    int t = threadIdx.x;
    int wv = t >> 6, l = t & 63;
    int dig = wv & 1, djq = wv >> 1;
    int itA = itp * 4 + dig * 2;
    int itB = itA + 1;
    int i0A = itA * 16, i0B = itB * 16;
    int jb = (jqp * 2 + djq) * 256;
    int jt0 = jb >> 5;           // first 32-j tile index
    int row = l & 15;  // A-frag row / B-frag col
    int kg  = l >> 4;  // k-chunk: k = kg*8 + e

    float h1A[H], h1B[H];
    #pragma unroll
    for (int h = 0; h < H; ++h) {
        h1A[h] = H1[(size_t)(b * H + h) * N + i0A + row];
        h1B[h] = H1[(size_t)(b * H + h) * N + i0B + row];
    }

    f32x4 accA[H][4] = {}; // [head][d-tile] for tile A
    f32x4 accB[H][4] = {}; // for tile B

    const unsigned int* AbpA = Abits + (size_t)b * 64 * 2048 + i0A + row; // + jt*2048
    const unsigned int* AbpB = Abits + (size_t)b * 64 * 2048 + i0B + row;
    const float4* H2r = (const float4*)(H2i + ((size_t)b * N + jb + kg * 8) * H);
    const us8* Hf = (const us8*)HpF + ((size_t)(b * H) * 64 + jt0) * 256 + l;

    unsigned int awA = AbpA[(size_t)jt0 * 2048];
    unsigned int awB = AbpB[(size_t)jt0 * 2048];

    for (int s = 0; s < NSTEP; ++s) {
        int sn = (s + 1 < NSTEP) ? (s + 1) : s;
        unsigned int awAn = AbpA[(size_t)(jt0 + sn) * 2048];
        unsigned int awBn = AbpB[(size_t)(jt0 + sn) * 2048];

        // ---- softmax for 8 pairs x 2 tiles, all 4 heads; shared H2 float4/pair ----
        bf16x8 afA[H], afB[H];
        #pragma unroll
        for (int e = 0; e < 8; ++e) {
            float4 h2 = H2r[s * 32 + e]; // heads 0..3 of pair j = jb+kg*8+s*32+e
            {
                bool on = (awA >> (kg * 8 + e)) & 1u;
                float v0 = h1A[0] + h2.x;
                float v1 = h1A[1] + h2.y;
                float v2 = h1A[2] + h2.z;
                float v3 = h1A[3] + h2.w;
                float s0 = on ? fmaxf(v0, 0.2f * v0) : 0.f;
                float s1 = on ? fmaxf(v1, 0.2f * v1) : 0.f;
                float s2 = on ? fmaxf(v2, 0.2f * v2) : 0.f;
                float s3 = on ? fmaxf(v3, 0.2f * v3) : 0.f;
                float e0 = EXP2(s0);
                float e1 = EXP2(s1);
                float e2 = EXP2(s2);
                float e3 = EXP2(s3);
                float zi = __builtin_amdgcn_rcpf(e0 + e1 + e2 + e3);
                afA[0][e] = (__bf16)(e0 * zi);
                afA[1][e] = (__bf16)(e1 * zi);
                afA[2][e] = (__bf16)(e2 * zi);
                afA[3][e] = (__bf16)(e3 * zi);
            }
            {
                bool on = (awB >> (kg * 8 + e)) & 1u;
                float v0 = h1B[0] + h2.x;
                float v1 = h1B[1] + h2.y;
                float v2 = h1B[2] + h2.z;
                float v3 = h1B[3] + h2.w;
                float s0 = on ? fmaxf(v0, 0.2f * v0) : 0.f;
                float s1 = on ? fmaxf(v1, 0.2f * v1) : 0.f;
                float s2 = on ? fmaxf(v2, 0.2f * v2) : 0.f;
                float s3 = on ? fmaxf(v3, 0.2f * v3) : 0.f;
                float e0 = EXP2(s0);
                float e1 = EXP2(s1);
                float e2 = EXP2(s2);
                float e3 = EXP2(s3);
                float zi = __builtin_amdgcn_rcpf(e0 + e1 + e2 + e3);
                afB[0][e] = (__bf16)(e0 * zi);
                afB[1][e] = (__bf16)(e1 * zi);
                afB[2][e] = (__bf16)(e2 * zi);
                afB[3][e] = (__bf16)(e3 * zi);
            }
        }

        // ---- MFMA: 4 heads x 4 d-tiles x 2 A-frags per B-load ----
        #pragma unroll
        for (int h = 0; h < H; ++h) {
            #pragma unroll
            for (int nt = 0; nt < 4; ++nt) {
                bf16x8 bfr = __builtin_bit_cast(bf16x8, Hf[(size_t)h * 64 * 256 + s * 256 + nt * 64]);
                accA[h][nt] = __builtin_amdgcn_mfma_f32_16x16x32_bf16(afA[h], bfr, accA[h][nt], 0, 0, 0);
                accB[h][nt] = __builtin_amdgcn_mfma_f32_16x16x32_bf16(afB[h], bfr, accB[h][nt], 0, 0, 0);
            }
        }

        awA = awAn;
        awB = awBn;
    }

    // ---- epilogue: djq-pair reduce through LDS; djq=0 writes the 2 chunks ----
    if (djq == 1) {
        #pragma unroll
        for (int h = 0; h < H; ++h)
            #pragma unroll
            for (int nt = 0; nt < 4; ++nt)
                #pragma unroll
                for (int r = 0; r < 4; ++r) {
                    int q = (h * 4 + nt) * 4 + r;
                    red[dig][0][q * 64 + l] = f2bf(accA[h][nt][r]);
                    red[dig][1][q * 64 + l] = f2bf(accB[h][nt][r]);
                }
    }
    __syncthreads();
    if (djq == 0) {
        unsigned short* cA = part + (((size_t)jqp * B + b) * 128 + itA) * CH;
        unsigned short* cB = part + (((size_t)jqp * B + b) * 128 + itB) * CH;
        #pragma unroll
        for (int h = 0; h < H; ++h)
            #pragma unroll
            for (int nt = 0; nt < 4; ++nt)
                #pragma unroll
                for (int r = 0; r < 4; ++r) {
                    int q = (h * 4 + nt) * 4 + r;
                    cA[(size_t)q * 64 + l] = f2bf(accA[h][nt][r] + bf2f(red[dig][0][q * 64 + l]));
                    cB[(size_t)q * 64 + l] = f2bf(accB[h][nt][r] + bf2f(red[dig][1][q * 64 + l]));
                }
    }
}

// ---------------- Kernel 3: MFMA out-GEMM, no LDS, no barriers ----------------
// Chunk layout: for (n' = h*512 + it*4 + kg, k = r*64 + nt*16 + rw):
//   chunk(jqp,b,it)[ ((h*4+nt)*4+r)*64 + kg*16 + rw ]
// A-frag (row m=l&15 -> it=it0+(m>>2), kg=m&3; k=ks*32+(l>>4)*8+e) = contiguous us8.
// B-frag from WoF (hi+lo pair, 2 MFMAs -> Wo exact to fp32).
__global__ __launch_bounds__(256) void k_out(const unsigned short* __restrict__ part,
                                             const unsigned short* __restrict__ WoF,
                                             const float* __restrict__ bo,
                                             float* __restrict__ out) {
    int bid = blockIdx.x;           // ((b*32)+itg)*2 + eh
    int eh  = bid & 1;
    int itg = (bid >> 1) & 31;
    int b   = bid >> 6;
    int t = threadIdx.x;
    int h = t >> 6, l = t & 63;
    int it0 = itg * 4;
    int m = l & 15;                 // A-row within 16-row tile
    int it = it0 + (m >> 2), kg = m & 3;
    int kh = l >> 4;

    const unsigned short* cb = part + ((size_t)b * 128 + it) * CH; // + jq*JSTRIDE
    const us8* wf = (const us8*)WoF;
    constexpr size_t JSTRIDE = (size_t)B * 128 * CH;

    f32x4 acc[8] = {};

    #pragma unroll
    for (int ks = 0; ks < 8; ++ks) {
        int k0 = ks * 32 + kh * 8;
        int nt = (k0 >> 4) & 3, r = k0 >> 6, rw0 = k0 & 15;
        int cidx = ((h * 4 + nt) * 4 + r) * 64 + kg * 16 + rw0;
        float s8[8] = {0.f, 0.f, 0.f, 0.f, 0.f, 0.f, 0.f, 0.f};
        #pragma unroll
        for (int jq = 0; jq < JQ; ++jq) {
            us8 p = *(const us8*)(cb + jq * JSTRIDE + cidx);
            #pragma unroll
            for (int e = 0; e < 8; ++e) s8[e] += bf2f(p[e]);
        }
        bf16x8 af;
        #pragma unroll
        for (int e = 0; e < 8; ++e) af[e] = (__bf16)s8[e];

        #pragma unroll
        for (int etl = 0; etl < 8; ++etl) {
            int et = eh * 8 + etl;
            bf16x8 bh = __builtin_bit_cast(bf16x8, wf[(size_t)(et * 8 + ks) * 64 + l]);
            bf16x8 bl = __builtin_bit_cast(bf16x8, wf[8192 + (size_t)(et * 8 + ks) * 64 + l]);
            acc[etl] = __builtin_amdgcn_mfma_f32_16x16x32_bf16(af, bh, acc[etl], 0, 0, 0);
            acc[etl] = __builtin_amdgcn_mfma_f32_16x16x32_bf16(af, bl, acc[etl], 0, 0, 0);
        }
    }

    // epilogue: C col=(l&15) within et-tile, row=(l>>4)*4+rr -> n'=h*512+(it0+(l>>4))*4+rr
    #pragma unroll
    for (int etl = 0; etl < 8; ++etl) {
        int e = (eh * 8 + etl) * 16 + (l & 15);
        float bias = bo[e];
        #pragma unroll
        for (int rr = 0; rr < 4; ++rr) {
            int nprime = h * 512 + (it0 + (l >> 4)) * 4 + rr;
            out[((size_t)b * N + nprime) * E + e] = acc[etl][rr] + bias;
        }
    }
}

extern "C" void kernel_launch(void* const* d_in, const int* in_sizes, int n_in,
                              void* d_out, int out_size, void* d_ws, size_t ws_size,
                              hipStream_t stream) {
    const float* X  = (const float*)d_in[0];
    const int*   A  = (const int*)d_in[1];
    const float* W  = (const float*)d_in[2];
    const float* a  = (const float*)d_in[3];
    const float* Wo = (const float*)d_in[4];
    const float* bo = (const float*)d_in[5];
    float* out = (float*)d_out;

    // ws: 4 partials (16.8MB), HpF (4.2MB), H1 (128KB), H2i (128KB), Abits (2MB),
    //     WoF (256KB), WfF (256KB)  => ~23.7MB total (proven envelope)
    unsigned short* wsu  = (unsigned short*)d_ws;
    unsigned short* part = wsu;
    unsigned short* HpF  = wsu + (size_t)JQ * B * 128 * CH;
    float* H1  = (float*)(HpF + (size_t)B * H * D * N);
    float* H2i = H1 + B * H * N;
    unsigned int* Abits = (unsigned int*)(H2i + (size_t)B * N * H);
    unsigned short* WoF = (unsigned short*)(Abits + (size_t)B * 64 * 2048);
    unsigned short* WfF = WoF + 2 * 8192 * 8;

    k_wconv<<<dim3(64), dim3(256), 0, stream>>>(Wo, W, WoF, WfF);
    k_prep<<<dim3(PROJ_BLKS + PACK_BLKS), dim3(256), 0, stream>>>(
        X, A, a, WfF, HpF, H1, H2i, Abits);
    k_agg<<<dim3(512), dim3(256), 0, stream>>>(Abits, H1, H2i, HpF, part);
    k_out<<<dim3(B * 32 * 2), dim3(256), 0, stream>>>(part, WoF, bo, out);
}

// Round 16
// 131.592 us; speedup vs baseline: 1.0075x; 1.0075x over previous
//
#include <hip/hip_runtime.h>

// Problem constants (fixed by setup_inputs)
constexpr int B = 4, N = 2048, I = 256, H = 4, D = 64, E = 256; // E = H*D
constexpr float LOG2E = 1.44269504088896340736f;

typedef __bf16 bf16x8 __attribute__((ext_vector_type(8)));
typedef float f32x4 __attribute__((ext_vector_type(4)));
typedef unsigned short us8 __attribute__((ext_vector_type(8)));

#if __has_builtin(__builtin_amdgcn_exp2f)
#define EXP2(x) __builtin_amdgcn_exp2f(x)
#else
#define EXP2(x) __expf((x) * 0.69314718055994530942f)
#endif

__device__ __forceinline__ unsigned short f2bf(float f) {
    unsigned u = __builtin_bit_cast(unsigned, f);
    u = (u + 0x7FFFu + ((u >> 16) & 1u)) >> 16;  // RNE
    return (unsigned short)u;
}
__device__ __forceinline__ float bf2f(unsigned short s) {
    return __builtin_bit_cast(float, (unsigned)s << 16);
}

constexpr int CH = 4096;       // u16 per (jh,b,it) chunk: 64 q-slots x 64 lanes
constexpr int PROJ_BLKS = 256; // 512 row-tiles x 2 eh / 4 waves
constexpr int PACK_BLKS = B * N / 4;

// ---------------- Kernel 0: weight conversions (must precede k_prep) ----------------
__global__ __launch_bounds__(256) void k_wconv(const float* __restrict__ Wo,
                                               const float* __restrict__ W,
                                               unsigned short* __restrict__ WoF,
                                               unsigned short* __restrict__ WfF) {
    int bid = blockIdx.x;
    int t = threadIdx.x;
    if (bid < 32) {
        int gid = bid * 256 + t;  // 8192
        int l = gid & 63, ks = (gid >> 6) & 7, et = gid >> 9;
        int row = et * 16 + (l & 15);
        int col = ks * 32 + (l >> 4) * 8;
        const float* src = Wo + (size_t)row * E + col;
        us8 hi, lo;
        #pragma unroll
        for (int e = 0; e < 8; ++e) {
            float v = src[e];
            unsigned short hb = f2bf(v);
            hi[e] = hb;
            lo[e] = f2bf(v - bf2f(hb));
        }
        ((us8*)WoF)[gid] = hi;
        ((us8*)WoF)[8192 + gid] = lo;
    } else {
        int gid = (bid - 32) * 256 + t;  // 8192
        int l = gid & 63, ks = (gid >> 6) & 7, et = gid >> 9;
        int c = et * 16 + (l & 15);
        int h = c >> 6, d = c & 63;
        int k0 = ks * 32 + (l >> 4) * 8;
        const float* src = W + ((size_t)h * I + k0) * D + d; // stride D per k
        us8 hi, lo;
        #pragma unroll
        for (int e = 0; e < 8; ++e) {
            float v = src[(size_t)e * D];
            unsigned short hb = f2bf(v);
            hi[e] = hb;
            lo[e] = f2bf(v - bf2f(hb));
        }
        ((us8*)WfF)[gid] = hi;
        ((us8*)WfF)[8192 + gid] = lo;
    }
}

// ---------------- Kernel 1 (fused prep): MFMA projection | adjacency pack ----------------
__global__ __launch_bounds__(256) void k_prep(const float* __restrict__ X,
                                              const int* __restrict__ A,
                                              const float* __restrict__ a,
                                              const unsigned short* __restrict__ WfF,
                                              unsigned short* __restrict__ HpF,
                                              float* __restrict__ H1,
                                              float* __restrict__ H2i,
                                              unsigned int* __restrict__ Abits) {
    __shared__ float ldsT[4][16 * 132]; // per-wave transpose scratch, pad stride 132

    int bid = blockIdx.x;
    int t = threadIdx.x;

    if (bid < PROJ_BLKS) {
        int wv = t >> 6, l = t & 63;
        int u = bid * 4 + wv;
        int eh = u & 1;
        int rt = u >> 1;
        int b = rt >> 7;
        int n0 = (rt & 127) * 16;
        int m = l & 15;   // A-frag row
        int kh = l >> 4;  // k-chunk

        const float* Xrow = X + ((size_t)b * N + n0 + m) * I + kh * 8;
        const us8* wf = (const us8*)WfF;

        f32x4 acc[8] = {};

        #pragma unroll
        for (int ks = 0; ks < 8; ++ks) {
            float4 xa = *(const float4*)(Xrow + ks * 32);
            float4 xb = *(const float4*)(Xrow + ks * 32 + 4);
            float xv[8] = {xa.x, xa.y, xa.z, xa.w, xb.x, xb.y, xb.z, xb.w};
            bf16x8 xh, xl;
            #pragma unroll
            for (int e = 0; e < 8; ++e) {
                unsigned short hb = f2bf(xv[e]);
                xh[e] = __builtin_bit_cast(__bf16, hb);
                xl[e] = __builtin_bit_cast(__bf16, f2bf(xv[e] - bf2f(hb)));
            }
            #pragma unroll
            for (int etl = 0; etl < 8; ++etl) {
                int et = eh * 8 + etl;
                bf16x8 wh = __builtin_bit_cast(bf16x8, wf[(size_t)(et * 8 + ks) * 64 + l]);
                bf16x8 wl = __builtin_bit_cast(bf16x8, wf[8192 + (size_t)(et * 8 + ks) * 64 + l]);
                acc[etl] = __builtin_amdgcn_mfma_f32_16x16x32_bf16(xh, wh, acc[etl], 0, 0, 0);
                acc[etl] = __builtin_amdgcn_mfma_f32_16x16x32_bf16(xl, wh, acc[etl], 0, 0, 0);
                acc[etl] = __builtin_amdgcn_mfma_f32_16x16x32_bf16(xh, wl, acc[etl], 0, 0, 0);
            }
        }

        // ---- H1/H2: dot with a over d, reduce over the 16 C-cols ----
        float a1v[8], a2v[8];
        #pragma unroll
        for (int etl = 0; etl < 8; ++etl) {
            int c = eh * 128 + etl * 16 + m; // C col = l&15
            int h = c >> 6, d = c & 63;
            a1v[etl] = a[h * (2 * D) + d];
            a2v[etl] = a[h * (2 * D) + D + d];
        }
        #pragma unroll
        for (int hh = 0; hh < 2; ++hh) {
            #pragma unroll
            for (int r = 0; r < 4; ++r) {
                float s1 = 0.f, s2 = 0.f;
                #pragma unroll
                for (int q = 0; q < 4; ++q) {
                    s1 += acc[hh * 4 + q][r] * a1v[hh * 4 + q];
                    s2 += acc[hh * 4 + q][r] * a2v[hh * 4 + q];
                }
                #pragma unroll
                for (int off = 1; off < 16; off <<= 1) {
                    s1 += __shfl_xor(s1, off, 64);
                    s2 += __shfl_xor(s2, off, 64);
                }
                if (m == 0) {
                    int hg = eh * 2 + hh;
                    int row = kh * 4 + r; // C row
                    H1[(size_t)(b * H + hg) * N + n0 + row] = s1 * LOG2E;
                    H2i[((size_t)b * N + n0 + row) * H + hg] = s2 * LOG2E;
                }
            }
        }

        // ---- HpF: per-wave LDS transpose (same-wave, no barrier needed) ----
        float* lw = ldsT[wv];
        #pragma unroll
        for (int etl = 0; etl < 8; ++etl)
            #pragma unroll
            for (int r = 0; r < 4; ++r)
                lw[(kh * 4 + r) * 132 + etl * 16 + m] = acc[etl][r];

        #pragma unroll
        for (int cc = 0; cc < 4; ++cc) {
            int ci = cc * 64 + l;
            int c_local = ci >> 1, q = ci & 1;
            us8 o;
            #pragma unroll
            for (int e = 0; e < 8; ++e)
                o[e] = f2bf(lw[(q * 8 + e) * 132 + c_local]);
            int cg = eh * 128 + c_local;
            int h = cg >> 6, d = cg & 63;
            int nb = n0 + q * 8;
            int jblk = nb >> 5, g = (nb >> 3) & 3;
            ((us8*)HpF)[(((size_t)(b * H + h) * 64 + jblk) * 4 + (d >> 4)) * 64 + ((d & 15) + 16 * g)] = o;
        }

    } else {
        // ---------------- adjacency pack: per-lane word, no ballot ----------------
        int blk = bid - PROJ_BLKS;
        int w = blk * 4 + (t >> 6); // row id = b*N + i
        int l = t & 63;
        int b = w >> 11;
        int i = w & 2047;
        const int4* Arow = (const int4*)(A + (size_t)w * N) + l * 8; // lane covers j in [l*32, l*32+32)
        unsigned word = 0;
        #pragma unroll
        for (int c = 0; c < 8; ++c) {
            int4 v = Arow[c];
            word |= ((unsigned)v.x << (c * 4 + 0)) | ((unsigned)v.y << (c * 4 + 1)) |
                    ((unsigned)v.z << (c * 4 + 2)) | ((unsigned)v.w << (c * 4 + 3));
        }
        Abits[(size_t)b * 64 * 2048 + (size_t)l * 2048 + i] = word;
    }
}

// ---------------- Kernel 2: barrier-free head-softmax + MFMA aggregation ----------------
// 1024 blocks x 4 waves (R13 structure, 58.4us verified). New vs R13:
//  * all 8 mask words preloaded into VGPRs (s-loop fully unrolled, no dyn indexing)
//  * H2 j-slice (4KB/wave) staged in LDS in the prologue (coalesced f4 loads + same-wave
//    ds_write, no barrier); per-step softmax reads are ds_read_b128 broadcasts.
//  * LDS overlaid with the reduce buffer; one extra barrier before reuse.
// Per-step global loads: only the 16 Hf B-frags (feed MFMA directly).
__global__ __launch_bounds__(256) void k_agg(const unsigned int* __restrict__ Abits,
                                             const float* __restrict__ H1,
                                             const float* __restrict__ H2i,
                                             const unsigned short* __restrict__ HpF,
                                             unsigned short* __restrict__ part) {
    __shared__ __align__(16) char smem[32768]; // phase 1: h2s[4][1024] f32; phase 2: red[4][CH] u16
    float* h2s = (float*)smem;
    unsigned short* red = (unsigned short*)smem;

    int bid = blockIdx.x;
    int b  = bid & 3;            // low bits -> XCD-locality
    int jh = (bid >> 2) & 1;
    int it = bid >> 3;
    int t = threadIdx.x;
    int wv = t >> 6, l = t & 63;
    int i0 = it * 16;
    int jb = jh * 1024 + wv * 256;
    int jt0 = jb >> 5;           // first 32-j tile index
    int row = l & 15;  // A-frag row / B-frag col
    int kg  = l >> 4;  // k-chunk: k = kg*8 + e

    // ---- prologue: stage this wave's H2 slice (256 j x 4 heads = 4KB) into LDS ----
    {
        const float4* src = (const float4*)(H2i + ((size_t)b * N + jb) * H);
        float4* dst = (float4*)(h2s + wv * 1024);
        #pragma unroll
        for (int c = 0; c < 4; ++c) dst[l + 64 * c] = src[l + 64 * c];
    }

    float h1v[H];
    #pragma unroll
    for (int h = 0; h < H; ++h) h1v[h] = H1[(size_t)(b * H + h) * N + i0 + row];

    // ---- preload all 8 mask words into registers ----
    const unsigned int* Abp = Abits + (size_t)b * 64 * 2048 + i0 + row;
    unsigned int aw[8];
    #pragma unroll
    for (int s = 0; s < 8; ++s) aw[s] = Abp[(size_t)(jt0 + s) * 2048];

    f32x4 acc[H][4] = {}; // [head][d-tile]

    const us8* Hf = (const us8*)HpF + ((size_t)(b * H) * 64 + jt0) * 256 + l;
    const float4* h2w = (const float4*)(h2s + wv * 1024) + kg * 8; // per-kg base

    #pragma unroll
    for (int s = 0; s < 8; ++s) {
        // ---- softmax for 8 pairs, all 4 heads; mask from regs, H2 from LDS ----
        bf16x8 af[H];
        #pragma unroll
        for (int e = 0; e < 8; ++e) {
            bool on = (aw[s] >> (kg * 8 + e)) & 1u;
            float4 h2 = h2w[s * 32 + e]; // heads 0..3 of pair j = jb+kg*8+s*32+e
            float v0 = h1v[0] + h2.x;
            float v1 = h1v[1] + h2.y;
            float v2 = h1v[2] + h2.z;
            float v3 = h1v[3] + h2.w;
            // leaky-relu in log2 domain; mask score to 0 (exp2(0)=1 -> w=0.25 exact)
            float s0 = on ? fmaxf(v0, 0.2f * v0) : 0.f;
            float s1 = on ? fmaxf(v1, 0.2f * v1) : 0.f;
            float s2 = on ? fmaxf(v2, 0.2f * v2) : 0.f;
            float s3 = on ? fmaxf(v3, 0.2f * v3) : 0.f;
            float e0 = EXP2(s0);
            float e1 = EXP2(s1);
            float e2 = EXP2(s2);
            float e3 = EXP2(s3);
            float zi = __builtin_amdgcn_rcpf(e0 + e1 + e2 + e3);
            af[0][e] = (__bf16)(e0 * zi);
            af[1][e] = (__bf16)(e1 * zi);
            af[2][e] = (__bf16)(e2 * zi);
            af[3][e] = (__bf16)(e3 * zi);
        }

        // ---- MFMA: 4 heads x 4 d-tiles; B-frag = coalesced 1KB load ----
        #pragma unroll
        for (int h = 0; h < H; ++h) {
            #pragma unroll
            for (int nt = 0; nt < 4; ++nt) {
                bf16x8 bfr = __builtin_bit_cast(bf16x8, Hf[(size_t)h * 64 * 256 + s * 256 + nt * 64]);
                acc[h][nt] = __builtin_amdgcn_mfma_f32_16x16x32_bf16(af[h], bfr, acc[h][nt], 0, 0, 0);
            }
        }
    }

    // ---- phase switch: H2 staging dead; reuse LDS as reduce buffer ----
    __syncthreads();
    #pragma unroll
    for (int h = 0; h < H; ++h)
        #pragma unroll
        for (int nt = 0; nt < 4; ++nt)
            #pragma unroll
            for (int r = 0; r < 4; ++r)
                red[(size_t)wv * CH + (((h * 4 + nt) * 4 + r)) * 64 + l] = f2bf(acc[h][nt][r]);
    __syncthreads();

    unsigned short* chunk = part + (((size_t)jh * B + b) * 128 + it) * CH;
    #pragma unroll
    for (int k = 0; k < CH / 256; ++k) { // 16
        int idx = t + 256 * k;
        float s = bf2f(red[0 * CH + idx]) + bf2f(red[1 * CH + idx]) +
                  bf2f(red[2 * CH + idx]) + bf2f(red[3 * CH + idx]);
        chunk[idx] = f2bf(s);
    }
}

// ---------------- Kernel 3: MFMA out-GEMM, no LDS, no barriers ----------------
__global__ __launch_bounds__(256) void k_out(const unsigned short* __restrict__ part,
                                             const unsigned short* __restrict__ WoF,
                                             const float* __restrict__ bo,
                                             float* __restrict__ out) {
    int bid = blockIdx.x;           // ((b*32)+itg)*2 + eh
    int eh  = bid & 1;
    int itg = (bid >> 1) & 31;
    int b   = bid >> 6;
    int t = threadIdx.x;
    int h = t >> 6, l = t & 63;
    int it0 = itg * 4;
    int m = l & 15;                 // A-row within 16-row tile
    int it = it0 + (m >> 2), kg = m & 3;
    int kh = l >> 4;

    const unsigned short* c0 = part + ((size_t)(0 * B + b) * 128 + it) * CH;
    const unsigned short* c1 = part + ((size_t)(1 * B + b) * 128 + it) * CH;
    const us8* wf = (const us8*)WoF;

    f32x4 acc[8] = {};

    #pragma unroll
    for (int ks = 0; ks < 8; ++ks) {
        int k0 = ks * 32 + kh * 8;
        int nt = (k0 >> 4) & 3, r = k0 >> 6, rw0 = k0 & 15;
        int cidx = ((h * 4 + nt) * 4 + r) * 64 + kg * 16 + rw0;
        us8 p0 = *(const us8*)(c0 + cidx);
        us8 p1 = *(const us8*)(c1 + cidx);
        bf16x8 af;
        #pragma unroll
        for (int e = 0; e < 8; ++e) af[e] = (__bf16)(bf2f(p0[e]) + bf2f(p1[e]));

        #pragma unroll
        for (int etl = 0; etl < 8; ++etl) {
            int et = eh * 8 + etl;
            bf16x8 bh = __builtin_bit_cast(bf16x8, wf[(size_t)(et * 8 + ks) * 64 + l]);
            bf16x8 bl = __builtin_bit_cast(bf16x8, wf[8192 + (size_t)(et * 8 + ks) * 64 + l]);
            acc[etl] = __builtin_amdgcn_mfma_f32_16x16x32_bf16(af, bh, acc[etl], 0, 0, 0);
            acc[etl] = __builtin_amdgcn_mfma_f32_16x16x32_bf16(af, bl, acc[etl], 0, 0, 0);
        }
    }

    #pragma unroll
    for (int etl = 0; etl < 8; ++etl) {
        int e = (eh * 8 + etl) * 16 + (l & 15);
        float bias = bo[e];
        #pragma unroll
        for (int rr = 0; rr < 4; ++rr) {
            int nprime = h * 512 + (it0 + (l >> 4)) * 4 + rr;
            out[((size_t)b * N + nprime) * E + e] = acc[etl][rr] + bias;
        }
    }
}

extern "C" void kernel_launch(void* const* d_in, const int* in_sizes, int n_in,
                              void* d_out, int out_size, void* d_ws, size_t ws_size,
                              hipStream_t stream) {
    const float* X  = (const float*)d_in[0];
    const int*   A  = (const int*)d_in[1];
    const float* W  = (const float*)d_in[2];
    const float* a  = (const float*)d_in[3];
    const float* Wo = (const float*)d_in[4];
    const float* bo = (const float*)d_in[5];
    float* out = (float*)d_out;

    // ws: 2 partials (8.4MB), HpF (4.2MB), H1 (128KB), H2i (128KB), Abits (2MB),
    //     WoF (256KB), WfF (256KB)
    unsigned short* wsu  = (unsigned short*)d_ws;
    unsigned short* part = wsu;
    unsigned short* HpF  = wsu + (size_t)2 * B * 128 * CH;
    float* H1  = (float*)(HpF + (size_t)B * H * D * N);
    float* H2i = H1 + B * H * N;
    unsigned int* Abits = (unsigned int*)(H2i + (size_t)B * N * H);
    unsigned short* WoF = (unsigned short*)(Abits + (size_t)B * 64 * 2048);
    unsigned short* WfF = WoF + 2 * 8192 * 8;

    k_wconv<<<dim3(64), dim3(256), 0, stream>>>(Wo, W, WoF, WfF);
    k_prep<<<dim3(PROJ_BLKS + PACK_BLKS), dim3(256), 0, stream>>>(
        X, A, a, WfF, HpF, H1, H2i, Abits);
    k_agg<<<dim3(2 * B * 128), dim3(256), 0, stream>>>(Abits, H1, H2i, HpF, part);
    k_out<<<dim3(B * 32 * 2), dim3(256), 0, stream>>>(part, WoF, bo, out);
}

// Round 17
// 130.920 us; speedup vs baseline: 1.0127x; 1.0051x over previous
//
#include <hip/hip_runtime.h>

// Problem constants (fixed by setup_inputs)
constexpr int B = 4, N = 2048, I = 256, H = 4, D = 64, E = 256; // E = H*D
constexpr float LOG2E = 1.44269504088896340736f;

typedef __bf16 bf16x8 __attribute__((ext_vector_type(8)));
typedef float f32x4 __attribute__((ext_vector_type(4)));
typedef unsigned short us8 __attribute__((ext_vector_type(8)));

#if __has_builtin(__builtin_amdgcn_exp2f)
#define EXP2(x) __builtin_amdgcn_exp2f(x)
#else
#define EXP2(x) __expf((x) * 0.69314718055994530942f)
#endif

__device__ __forceinline__ unsigned short f2bf(float f) {
    unsigned u = __builtin_bit_cast(unsigned, f);
    u = (u + 0x7FFFu + ((u >> 16) & 1u)) >> 16;  // RNE
    return (unsigned short)u;
}
__device__ __forceinline__ float bf2f(unsigned short s) {
    return __builtin_bit_cast(float, (unsigned)s << 16);
}

constexpr int CH = 4096;       // u16 per (jh,b,it) chunk: 64 q-slots x 64 lanes
constexpr int PROJ_BLKS = 256; // 512 row-tiles x 2 eh / 4 waves
constexpr int PACK_BLKS = B * N / 4;

// ---------------- Kernel 0: weight conversions (must precede k_prep) ----------------
__global__ __launch_bounds__(256) void k_wconv(const float* __restrict__ Wo,
                                               const float* __restrict__ W,
                                               unsigned short* __restrict__ WoF,
                                               unsigned short* __restrict__ WfF) {
    int bid = blockIdx.x;
    int t = threadIdx.x;
    if (bid < 32) {
        int gid = bid * 256 + t;  // 8192
        int l = gid & 63, ks = (gid >> 6) & 7, et = gid >> 9;
        int row = et * 16 + (l & 15);
        int col = ks * 32 + (l >> 4) * 8;
        const float* src = Wo + (size_t)row * E + col;
        us8 hi, lo;
        #pragma unroll
        for (int e = 0; e < 8; ++e) {
            float v = src[e];
            unsigned short hb = f2bf(v);
            hi[e] = hb;
            lo[e] = f2bf(v - bf2f(hb));
        }
        ((us8*)WoF)[gid] = hi;
        ((us8*)WoF)[8192 + gid] = lo;
    } else {
        int gid = (bid - 32) * 256 + t;  // 8192
        int l = gid & 63, ks = (gid >> 6) & 7, et = gid >> 9;
        int c = et * 16 + (l & 15);
        int h = c >> 6, d = c & 63;
        int k0 = ks * 32 + (l >> 4) * 8;
        const float* src = W + ((size_t)h * I + k0) * D + d; // stride D per k
        us8 hi, lo;
        #pragma unroll
        for (int e = 0; e < 8; ++e) {
            float v = src[(size_t)e * D];
            unsigned short hb = f2bf(v);
            hi[e] = hb;
            lo[e] = f2bf(v - bf2f(hb));
        }
        ((us8*)WfF)[gid] = hi;
        ((us8*)WfF)[8192 + gid] = lo;
    }
}

// ---------------- Kernel 1 (fused prep): MFMA projection | adjacency pack ----------------
// proj blocks [0,256): MFMA projection (verified R12 structure).
// pack blocks [256,2304): one wave per (b,i) row. Lane l, iter c: COALESCED int4 load
//   #(c*64+l) (1KB/instr); its 4 j-bits -> nibble ((l&7)*4) of word c*8+(l>>3);
//   3x shfl_xor OR assembles the word in the 8-lane group; lane l&7==0 writes.
//   Abits is ROW-MAJOR [b][i][jw] -> pack writes are 8x32B contiguous per instr.
__global__ __launch_bounds__(256) void k_prep(const float* __restrict__ X,
                                              const int* __restrict__ A,
                                              const float* __restrict__ a,
                                              const unsigned short* __restrict__ WfF,
                                              unsigned short* __restrict__ HpF,
                                              float* __restrict__ H1,
                                              float* __restrict__ H2i,
                                              unsigned int* __restrict__ Abits) {
    __shared__ float ldsT[4][16 * 132]; // per-wave transpose scratch, pad stride 132

    int bid = blockIdx.x;
    int t = threadIdx.x;

    if (bid < PROJ_BLKS) {
        int wv = t >> 6, l = t & 63;
        int u = bid * 4 + wv;
        int eh = u & 1;
        int rt = u >> 1;
        int b = rt >> 7;
        int n0 = (rt & 127) * 16;
        int m = l & 15;   // A-frag row
        int kh = l >> 4;  // k-chunk

        const float* Xrow = X + ((size_t)b * N + n0 + m) * I + kh * 8;
        const us8* wf = (const us8*)WfF;

        f32x4 acc[8] = {};

        #pragma unroll
        for (int ks = 0; ks < 8; ++ks) {
            float4 xa = *(const float4*)(Xrow + ks * 32);
            float4 xb = *(const float4*)(Xrow + ks * 32 + 4);
            float xv[8] = {xa.x, xa.y, xa.z, xa.w, xb.x, xb.y, xb.z, xb.w};
            bf16x8 xh, xl;
            #pragma unroll
            for (int e = 0; e < 8; ++e) {
                unsigned short hb = f2bf(xv[e]);
                xh[e] = __builtin_bit_cast(__bf16, hb);
                xl[e] = __builtin_bit_cast(__bf16, f2bf(xv[e] - bf2f(hb)));
            }
            #pragma unroll
            for (int etl = 0; etl < 8; ++etl) {
                int et = eh * 8 + etl;
                bf16x8 wh = __builtin_bit_cast(bf16x8, wf[(size_t)(et * 8 + ks) * 64 + l]);
                bf16x8 wl = __builtin_bit_cast(bf16x8, wf[8192 + (size_t)(et * 8 + ks) * 64 + l]);
                acc[etl] = __builtin_amdgcn_mfma_f32_16x16x32_bf16(xh, wh, acc[etl], 0, 0, 0);
                acc[etl] = __builtin_amdgcn_mfma_f32_16x16x32_bf16(xl, wh, acc[etl], 0, 0, 0);
                acc[etl] = __builtin_amdgcn_mfma_f32_16x16x32_bf16(xh, wl, acc[etl], 0, 0, 0);
            }
        }

        // ---- H1/H2: dot with a over d, reduce over the 16 C-cols ----
        float a1v[8], a2v[8];
        #pragma unroll
        for (int etl = 0; etl < 8; ++etl) {
            int c = eh * 128 + etl * 16 + m; // C col = l&15
            int h = c >> 6, d = c & 63;
            a1v[etl] = a[h * (2 * D) + d];
            a2v[etl] = a[h * (2 * D) + D + d];
        }
        #pragma unroll
        for (int hh = 0; hh < 2; ++hh) {
            #pragma unroll
            for (int r = 0; r < 4; ++r) {
                float s1 = 0.f, s2 = 0.f;
                #pragma unroll
                for (int q = 0; q < 4; ++q) {
                    s1 += acc[hh * 4 + q][r] * a1v[hh * 4 + q];
                    s2 += acc[hh * 4 + q][r] * a2v[hh * 4 + q];
                }
                #pragma unroll
                for (int off = 1; off < 16; off <<= 1) {
                    s1 += __shfl_xor(s1, off, 64);
                    s2 += __shfl_xor(s2, off, 64);
                }
                if (m == 0) {
                    int hg = eh * 2 + hh;
                    int row = kh * 4 + r; // C row
                    H1[(size_t)(b * H + hg) * N + n0 + row] = s1 * LOG2E;
                    H2i[((size_t)b * N + n0 + row) * H + hg] = s2 * LOG2E;
                }
            }
        }

        // ---- HpF: per-wave LDS transpose (same-wave, no barrier needed) ----
        float* lw = ldsT[wv];
        #pragma unroll
        for (int etl = 0; etl < 8; ++etl)
            #pragma unroll
            for (int r = 0; r < 4; ++r)
                lw[(kh * 4 + r) * 132 + etl * 16 + m] = acc[etl][r];

        #pragma unroll
        for (int cc = 0; cc < 4; ++cc) {
            int ci = cc * 64 + l;
            int c_local = ci >> 1, q = ci & 1;
            us8 o;
            #pragma unroll
            for (int e = 0; e < 8; ++e)
                o[e] = f2bf(lw[(q * 8 + e) * 132 + c_local]);
            int cg = eh * 128 + c_local;
            int h = cg >> 6, d = cg & 63;
            int nb = n0 + q * 8;
            int jblk = nb >> 5, g = (nb >> 3) & 3;
            ((us8*)HpF)[(((size_t)(b * H + h) * 64 + jblk) * 4 + (d >> 4)) * 64 + ((d & 15) + 16 * g)] = o;
        }

    } else {
        // ---------------- adjacency pack: coalesced loads + 8-lane shfl-OR ----------------
        int blk = bid - PROJ_BLKS;
        int w = blk * 4 + (t >> 6); // row id = b*N + i
        int l = t & 63;
        const int4* Arow = (const int4*)(A + (size_t)w * N);
        unsigned int* dst = Abits + (size_t)w * 64; // row-major [b][i][jw]
        #pragma unroll
        for (int c = 0; c < 8; ++c) {
            int4 v = Arow[c * 64 + l]; // coalesced: ints 4*(c*64+l)..+4
            unsigned nib = ((unsigned)v.x | ((unsigned)v.y << 1) |
                            ((unsigned)v.z << 2) | ((unsigned)v.w << 3)) << ((l & 7) * 4);
            nib |= __shfl_xor((int)nib, 1, 64);
            nib |= __shfl_xor((int)nib, 2, 64);
            nib |= __shfl_xor((int)nib, 4, 64);
            if ((l & 7) == 0) dst[c * 8 + (l >> 3)] = nib; // 8x32B contiguous
        }
    }
}

// ---------------- Kernel 2: barrier-free head-softmax + MFMA aggregation (R13 body) ----------------
// 1024 blocks x 4 waves. XCD-locality: bid&7 = (jh<<2)|b -> L2-resident working set.
// Wave wv covers j in [jh*1024+wv*256,+256), 8 steps of 32 j; lane l owns A-frag slots
// (row=l&15, k=(l>>4)*8+e); 4-head softmax once per pair in regs; masks preloaded as
// two uint4 (row-major Abits); H2 global loads (compiler prefetches). End LDS reduce.
__global__ __launch_bounds__(256) void k_agg(const unsigned int* __restrict__ Abits,
                                             const float* __restrict__ H1,
                                             const float* __restrict__ H2i,
                                             const unsigned short* __restrict__ HpF,
                                             unsigned short* __restrict__ part) {
    __shared__ unsigned short red[4][CH]; // 32 KB

    int bid = blockIdx.x;
    int b  = bid & 3;            // low bits -> XCD-locality
    int jh = (bid >> 2) & 1;
    int it = bid >> 3;
    int t = threadIdx.x;
    int wv = t >> 6, l = t & 63;
    int i0 = it * 16;
    int jb = jh * 1024 + wv * 256;
    int jt0 = jb >> 5;           // first 32-j tile index (multiple of 8)
    int row = l & 15;  // A-frag row / B-frag col
    int kg  = l >> 4;  // k-chunk: k = kg*8 + e

    float h1v[H];
    #pragma unroll
    for (int h = 0; h < H; ++h) h1v[h] = H1[(size_t)(b * H + h) * N + i0 + row];

    // ---- preload all 8 mask words (row-major Abits, two aligned uint4) ----
    const unsigned int* Abp = Abits + ((size_t)b * 2048 + i0 + row) * 64;
    uint4 awa = *(const uint4*)(Abp + jt0);
    uint4 awb = *(const uint4*)(Abp + jt0 + 4);
    unsigned aw[8] = {awa.x, awa.y, awa.z, awa.w, awb.x, awb.y, awb.z, awb.w};

    f32x4 acc[H][4] = {}; // [head][d-tile]

    const float4* H2r = (const float4*)(H2i + ((size_t)b * N + jb + kg * 8) * H);
    const us8* Hf = (const us8*)HpF + ((size_t)(b * H) * 64 + jt0) * 256 + l;

    #pragma unroll
    for (int s = 0; s < 8; ++s) {
        // ---- softmax for 8 pairs, all 4 heads; mask from regs, one float4 H2/pair ----
        bf16x8 af[H];
        #pragma unroll
        for (int e = 0; e < 8; ++e) {
            bool on = (aw[s] >> (kg * 8 + e)) & 1u;
            float4 h2 = H2r[s * 32 + e]; // heads 0..3 of pair j = jb+kg*8+s*32+e
            float v0 = h1v[0] + h2.x;
            float v1 = h1v[1] + h2.y;
            float v2 = h1v[2] + h2.z;
            float v3 = h1v[3] + h2.w;
            // leaky-relu in log2 domain; mask score to 0 (exp2(0)=1 -> w=0.25 exact)
            float s0 = on ? fmaxf(v0, 0.2f * v0) : 0.f;
            float s1 = on ? fmaxf(v1, 0.2f * v1) : 0.f;
            float s2 = on ? fmaxf(v2, 0.2f * v2) : 0.f;
            float s3 = on ? fmaxf(v3, 0.2f * v3) : 0.f;
            float e0 = EXP2(s0);
            float e1 = EXP2(s1);
            float e2 = EXP2(s2);
            float e3 = EXP2(s3);
            float zi = __builtin_amdgcn_rcpf(e0 + e1 + e2 + e3);
            af[0][e] = (__bf16)(e0 * zi);
            af[1][e] = (__bf16)(e1 * zi);
            af[2][e] = (__bf16)(e2 * zi);
            af[3][e] = (__bf16)(e3 * zi);
        }

        // ---- MFMA: 4 heads x 4 d-tiles; B-frag = coalesced 1KB load ----
        #pragma unroll
        for (int h = 0; h < H; ++h) {
            #pragma unroll
            for (int nt = 0; nt < 4; ++nt) {
                bf16x8 bfr = __builtin_bit_cast(bf16x8, Hf[(size_t)h * 64 * 256 + s * 256 + nt * 64]);
                acc[h][nt] = __builtin_amdgcn_mfma_f32_16x16x32_bf16(af[h], bfr, acc[h][nt], 0, 0, 0);
            }
        }
    }

    // ---- end-of-kernel reduce: each wave dumps bf16 to its LDS slot; sum 4 slots ----
    #pragma unroll
    for (int h = 0; h < H; ++h)
        #pragma unroll
        for (int nt = 0; nt < 4; ++nt)
            #pragma unroll
            for (int r = 0; r < 4; ++r)
                red[wv][(((h * 4 + nt) * 4 + r)) * 64 + l] = f2bf(acc[h][nt][r]);
    __syncthreads();

    unsigned short* chunk = part + (((size_t)jh * B + b) * 128 + it) * CH;
    #pragma unroll
    for (int k = 0; k < CH / 256; ++k) { // 16
        int idx = t + 256 * k;
        float s = bf2f(red[0][idx]) + bf2f(red[1][idx]) + bf2f(red[2][idx]) + bf2f(red[3][idx]);
        chunk[idx] = f2bf(s);
    }
}

// ---------------- Kernel 3: MFMA out-GEMM, no LDS, no barriers ----------------
__global__ __launch_bounds__(256) void k_out(const unsigned short* __restrict__ part,
                                             const unsigned short* __restrict__ WoF,
                                             const float* __restrict__ bo,
                                             float* __restrict__ out) {
    int bid = blockIdx.x;           // ((b*32)+itg)*2 + eh
    int eh  = bid & 1;
    int itg = (bid >> 1) & 31;
    int b   = bid >> 6;
    int t = threadIdx.x;
    int h = t >> 6, l = t & 63;
    int it0 = itg * 4;
    int m = l & 15;                 // A-row within 16-row tile
    int it = it0 + (m >> 2), kg = m & 3;
    int kh = l >> 4;

    const unsigned short* c0 = part + ((size_t)(0 * B + b) * 128 + it) * CH;
    const unsigned short* c1 = part + ((size_t)(1 * B + b) * 128 + it) * CH;
    const us8* wf = (const us8*)WoF;

    f32x4 acc[8] = {};

    #pragma unroll
    for (int ks = 0; ks < 8; ++ks) {
        int k0 = ks * 32 + kh * 8;
        int nt = (k0 >> 4) & 3, r = k0 >> 6, rw0 = k0 & 15;
        int cidx = ((h * 4 + nt) * 4 + r) * 64 + kg * 16 + rw0;
        us8 p0 = *(const us8*)(c0 + cidx);
        us8 p1 = *(const us8*)(c1 + cidx);
        bf16x8 af;
        #pragma unroll
        for (int e = 0; e < 8; ++e) af[e] = (__bf16)(bf2f(p0[e]) + bf2f(p1[e]));

        #pragma unroll
        for (int etl = 0; etl < 8; ++etl) {
            int et = eh * 8 + etl;
            bf16x8 bh = __builtin_bit_cast(bf16x8, wf[(size_t)(et * 8 + ks) * 64 + l]);
            bf16x8 bl = __builtin_bit_cast(bf16x8, wf[8192 + (size_t)(et * 8 + ks) * 64 + l]);
            acc[etl] = __builtin_amdgcn_mfma_f32_16x16x32_bf16(af, bh, acc[etl], 0, 0, 0);
            acc[etl] = __builtin_amdgcn_mfma_f32_16x16x32_bf16(af, bl, acc[etl], 0, 0, 0);
        }
    }

    #pragma unroll
    for (int etl = 0; etl < 8; ++etl) {
        int e = (eh * 8 + etl) * 16 + (l & 15);
        float bias = bo[e];
        #pragma unroll
        for (int rr = 0; rr < 4; ++rr) {
            int nprime = h * 512 + (it0 + (l >> 4)) * 4 + rr;
            out[((size_t)b * N + nprime) * E + e] = acc[etl][rr] + bias;
        }
    }
}

extern "C" void kernel_launch(void* const* d_in, const int* in_sizes, int n_in,
                              void* d_out, int out_size, void* d_ws, size_t ws_size,
                              hipStream_t stream) {
    const float* X  = (const float*)d_in[0];
    const int*   A  = (const int*)d_in[1];
    const float* W  = (const float*)d_in[2];
    const float* a  = (const float*)d_in[3];
    const float* Wo = (const float*)d_in[4];
    const float* bo = (const float*)d_in[5];
    float* out = (float*)d_out;

    // ws: 2 partials (8.4MB), HpF (4.2MB), H1 (128KB), H2i (128KB), Abits (2MB),
    //     WoF (256KB), WfF (256KB)
    unsigned short* wsu  = (unsigned short*)d_ws;
    unsigned short* part = wsu;
    unsigned short* HpF  = wsu + (size_t)2 * B * 128 * CH;
    float* H1  = (float*)(HpF + (size_t)B * H * D * N);
    float* H2i = H1 + B * H * N;
    unsigned int* Abits = (unsigned int*)(H2i + (size_t)B * N * H);
    unsigned short* WoF = (unsigned short*)(Abits + (size_t)B * 64 * 2048);
    unsigned short* WfF = WoF + 2 * 8192 * 8;

    k_wconv<<<dim3(64), dim3(256), 0, stream>>>(Wo, W, WoF, WfF);
    k_prep<<<dim3(PROJ_BLKS + PACK_BLKS), dim3(256), 0, stream>>>(
        X, A, a, WfF, HpF, H1, H2i, Abits);
    k_agg<<<dim3(2 * B * 128), dim3(256), 0, stream>>>(Abits, H1, H2i, HpF, part);
    k_out<<<dim3(B * 32 * 2), dim3(256), 0, stream>>>(part, WoF, bo, out);
}

// Round 18
// 105.771 us; speedup vs baseline: 1.2535x; 1.2378x over previous
//
#include <hip/hip_runtime.h>

// Problem constants (fixed by setup_inputs)
constexpr int B = 4, N = 2048, I = 256, H = 4, D = 64, E = 256; // E = H*D
constexpr float LOG2E = 1.44269504088896340736f;

typedef __bf16 bf16x8 __attribute__((ext_vector_type(8)));
typedef float f32x4 __attribute__((ext_vector_type(4)));
typedef unsigned short us8 __attribute__((ext_vector_type(8)));

#if __has_builtin(__builtin_amdgcn_exp2f)
#define EXP2(x) __builtin_amdgcn_exp2f(x)
#else
#define EXP2(x) __expf((x) * 0.69314718055994530942f)
#endif

__device__ __forceinline__ unsigned short f2bf(float f) {
    unsigned u = __builtin_bit_cast(unsigned, f);
    u = (u + 0x7FFFu + ((u >> 16) & 1u)) >> 16;  // RNE
    return (unsigned short)u;
}
__device__ __forceinline__ float bf2f(unsigned short s) {
    return __builtin_bit_cast(float, (unsigned)s << 16);
}

constexpr int CH = 4096;       // u16 per (jh,b,it) chunk: 64 q-slots x 64 lanes
constexpr int PROJ_BLKS = 256; // 512 row-tiles x 2 eh / 4 waves
constexpr int PACK_BLKS = B * N / 4;

// ---------------- Kernel 0: weight conversions (must precede k_prep) ----------------
__global__ __launch_bounds__(256) void k_wconv(const float* __restrict__ Wo,
                                               const float* __restrict__ W,
                                               unsigned short* __restrict__ WoF,
                                               unsigned short* __restrict__ WfF) {
    int bid = blockIdx.x;
    int t = threadIdx.x;
    if (bid < 32) {
        int gid = bid * 256 + t;  // 8192
        int l = gid & 63, ks = (gid >> 6) & 7, et = gid >> 9;
        int row = et * 16 + (l & 15);
        int col = ks * 32 + (l >> 4) * 8;
        const float* src = Wo + (size_t)row * E + col;
        us8 hi, lo;
        #pragma unroll
        for (int e = 0; e < 8; ++e) {
            float v = src[e];
            unsigned short hb = f2bf(v);
            hi[e] = hb;
            lo[e] = f2bf(v - bf2f(hb));
        }
        ((us8*)WoF)[gid] = hi;
        ((us8*)WoF)[8192 + gid] = lo;
    } else {
        int gid = (bid - 32) * 256 + t;  // 8192
        int l = gid & 63, ks = (gid >> 6) & 7, et = gid >> 9;
        int c = et * 16 + (l & 15);
        int h = c >> 6, d = c & 63;
        int k0 = ks * 32 + (l >> 4) * 8;
        const float* src = W + ((size_t)h * I + k0) * D + d; // stride D per k
        us8 hi, lo;
        #pragma unroll
        for (int e = 0; e < 8; ++e) {
            float v = src[(size_t)e * D];
            unsigned short hb = f2bf(v);
            hi[e] = hb;
            lo[e] = f2bf(v - bf2f(hb));
        }
        ((us8*)WfF)[gid] = hi;
        ((us8*)WfF)[8192 + gid] = lo;
    }
}

// ---------------- Kernel 1 (fused prep): MFMA projection | adjacency pack ----------------
// proj blocks [0,256): MFMA projection (verified R12 structure).
// pack blocks [256,2304): one wave per (b,i) row. Lane l, iter c: COALESCED int4 load
//   #(c*64+l) (1KB/instr); its 4 j-bits -> nibble ((l&7)*4) of word jw=c*8+(l>>3);
//   3x shfl_xor OR assembles the word; lane l&7==0 writes COLUMN-major Abits[b][jw][i]
//   (scattered 4B writes, tiny volume; k_agg's per-step mask reads stay 16-contiguous).
__global__ __launch_bounds__(256) void k_prep(const float* __restrict__ X,
                                              const int* __restrict__ A,
                                              const float* __restrict__ a,
                                              const unsigned short* __restrict__ WfF,
                                              unsigned short* __restrict__ HpF,
                                              float* __restrict__ H1,
                                              float* __restrict__ H2i,
                                              unsigned int* __restrict__ Abits) {
    __shared__ float ldsT[4][16 * 132]; // per-wave transpose scratch, pad stride 132

    int bid = blockIdx.x;
    int t = threadIdx.x;

    if (bid < PROJ_BLKS) {
        int wv = t >> 6, l = t & 63;
        int u = bid * 4 + wv;
        int eh = u & 1;
        int rt = u >> 1;
        int b = rt >> 7;
        int n0 = (rt & 127) * 16;
        int m = l & 15;   // A-frag row
        int kh = l >> 4;  // k-chunk

        const float* Xrow = X + ((size_t)b * N + n0 + m) * I + kh * 8;
        const us8* wf = (const us8*)WfF;

        f32x4 acc[8] = {};

        #pragma unroll
        for (int ks = 0; ks < 8; ++ks) {
            float4 xa = *(const float4*)(Xrow + ks * 32);
            float4 xb = *(const float4*)(Xrow + ks * 32 + 4);
            float xv[8] = {xa.x, xa.y, xa.z, xa.w, xb.x, xb.y, xb.z, xb.w};
            bf16x8 xh, xl;
            #pragma unroll
            for (int e = 0; e < 8; ++e) {
                unsigned short hb = f2bf(xv[e]);
                xh[e] = __builtin_bit_cast(__bf16, hb);
                xl[e] = __builtin_bit_cast(__bf16, f2bf(xv[e] - bf2f(hb)));
            }
            #pragma unroll
            for (int etl = 0; etl < 8; ++etl) {
                int et = eh * 8 + etl;
                bf16x8 wh = __builtin_bit_cast(bf16x8, wf[(size_t)(et * 8 + ks) * 64 + l]);
                bf16x8 wl = __builtin_bit_cast(bf16x8, wf[8192 + (size_t)(et * 8 + ks) * 64 + l]);
                acc[etl] = __builtin_amdgcn_mfma_f32_16x16x32_bf16(xh, wh, acc[etl], 0, 0, 0);
                acc[etl] = __builtin_amdgcn_mfma_f32_16x16x32_bf16(xl, wh, acc[etl], 0, 0, 0);
                acc[etl] = __builtin_amdgcn_mfma_f32_16x16x32_bf16(xh, wl, acc[etl], 0, 0, 0);
            }
        }

        // ---- H1/H2: dot with a over d, reduce over the 16 C-cols ----
        float a1v[8], a2v[8];
        #pragma unroll
        for (int etl = 0; etl < 8; ++etl) {
            int c = eh * 128 + etl * 16 + m; // C col = l&15
            int h = c >> 6, d = c & 63;
            a1v[etl] = a[h * (2 * D) + d];
            a2v[etl] = a[h * (2 * D) + D + d];
        }
        #pragma unroll
        for (int hh = 0; hh < 2; ++hh) {
            #pragma unroll
            for (int r = 0; r < 4; ++r) {
                float s1 = 0.f, s2 = 0.f;
                #pragma unroll
                for (int q = 0; q < 4; ++q) {
                    s1 += acc[hh * 4 + q][r] * a1v[hh * 4 + q];
                    s2 += acc[hh * 4 + q][r] * a2v[hh * 4 + q];
                }
                #pragma unroll
                for (int off = 1; off < 16; off <<= 1) {
                    s1 += __shfl_xor(s1, off, 64);
                    s2 += __shfl_xor(s2, off, 64);
                }
                if (m == 0) {
                    int hg = eh * 2 + hh;
                    int row = kh * 4 + r; // C row
                    H1[(size_t)(b * H + hg) * N + n0 + row] = s1 * LOG2E;
                    H2i[((size_t)b * N + n0 + row) * H + hg] = s2 * LOG2E;
                }
            }
        }

        // ---- HpF: per-wave LDS transpose (same-wave, no barrier needed) ----
        float* lw = ldsT[wv];
        #pragma unroll
        for (int etl = 0; etl < 8; ++etl)
            #pragma unroll
            for (int r = 0; r < 4; ++r)
                lw[(kh * 4 + r) * 132 + etl * 16 + m] = acc[etl][r];

        #pragma unroll
        for (int cc = 0; cc < 4; ++cc) {
            int ci = cc * 64 + l;
            int c_local = ci >> 1, q = ci & 1;
            us8 o;
            #pragma unroll
            for (int e = 0; e < 8; ++e)
                o[e] = f2bf(lw[(q * 8 + e) * 132 + c_local]);
            int cg = eh * 128 + c_local;
            int h = cg >> 6, d = cg & 63;
            int nb = n0 + q * 8;
            int jblk = nb >> 5, g = (nb >> 3) & 3;
            ((us8*)HpF)[(((size_t)(b * H + h) * 64 + jblk) * 4 + (d >> 4)) * 64 + ((d & 15) + 16 * g)] = o;
        }

    } else {
        // ---------------- adjacency pack: coalesced loads + 8-lane shfl-OR ----------------
        int blk = bid - PROJ_BLKS;
        int w = blk * 4 + (t >> 6); // row id = b*N + i
        int l = t & 63;
        int b = w >> 11;
        int i = w & 2047;
        const int4* Arow = (const int4*)(A + (size_t)w * N);
        unsigned int* dstb = Abits + (size_t)b * 64 * 2048 + i; // column-major [b][jw][i]
        #pragma unroll
        for (int c = 0; c < 8; ++c) {
            int4 v = Arow[c * 64 + l]; // coalesced: ints 4*(c*64+l)..+4
            unsigned nib = ((unsigned)v.x | ((unsigned)v.y << 1) |
                            ((unsigned)v.z << 2) | ((unsigned)v.w << 3)) << ((l & 7) * 4);
            nib |= __shfl_xor((int)nib, 1, 64);
            nib |= __shfl_xor((int)nib, 2, 64);
            nib |= __shfl_xor((int)nib, 4, 64);
            if ((l & 7) == 0) dstb[(size_t)(c * 8 + (l >> 3)) * 2048] = nib;
        }
    }
}

// ---------------- Kernel 2: barrier-free head-softmax + MFMA aggregation (R13 body) ----------------
// 1024 blocks x 4 waves. XCD-locality: bid&7 = (jh<<2)|b -> L2-resident working set
// (HpF(b) 1MB + Abits(b,jh) + H2i(b)). Wave wv covers j in [jh*1024+wv*256,+256),
// 8 steps of 32 j; lane l owns A-frag slots (row=l&15, k=(l>>4)*8+e); 4-head softmax
// once per pair in regs; unroll-2 with mask-word rotation (verified 58.4us schedule).
// s_setprio(1) around the MFMA cluster (independent waves -> attn-like, m191 +4%).
constexpr int NSTEP = 8;

__global__ __launch_bounds__(256) void k_agg(const unsigned int* __restrict__ Abits,
                                             const float* __restrict__ H1,
                                             const float* __restrict__ H2i,
                                             const unsigned short* __restrict__ HpF,
                                             unsigned short* __restrict__ part) {
    __shared__ unsigned short red[4][CH]; // 32 KB

    int bid = blockIdx.x;
    int b  = bid & 3;            // low bits -> XCD-locality
    int jh = (bid >> 2) & 1;
    int it = bid >> 3;
    int t = threadIdx.x;
    int wv = t >> 6, l = t & 63;
    int i0 = it * 16;
    int jb = jh * 1024 + wv * 256;
    int jt0 = jb >> 5;           // first 32-j tile index
    int row = l & 15;  // A-frag row / B-frag col
    int kg  = l >> 4;  // k-chunk: k = kg*8 + e

    float h1v[H];
    #pragma unroll
    for (int h = 0; h < H; ++h) h1v[h] = H1[(size_t)(b * H + h) * N + i0 + row];

    f32x4 acc[H][4] = {}; // [head][d-tile]

    const unsigned int* Abp = Abits + (size_t)b * 64 * 2048 + i0 + row; // + jt*2048
    const float4* H2r = (const float4*)(H2i + ((size_t)b * N + jb + kg * 8) * H);
    const us8* Hf = (const us8*)HpF + ((size_t)(b * H) * 64 + jt0) * 256 + l;

    unsigned int aw = Abp[(size_t)jt0 * 2048];

    #pragma unroll 2
    for (int s = 0; s < NSTEP; ++s) {
        int sn = (s + 1 < NSTEP) ? (s + 1) : s;
        unsigned int awn = Abp[(size_t)(jt0 + sn) * 2048];

        // ---- softmax for 8 pairs, all 4 heads; bit-test mask, one float4 H2/pair ----
        bf16x8 af[H];
        #pragma unroll
        for (int e = 0; e < 8; ++e) {
            bool on = (aw >> (kg * 8 + e)) & 1u;
            float4 h2 = H2r[s * 32 + e]; // heads 0..3 of pair j = jb+kg*8+s*32+e
            float v0 = h1v[0] + h2.x;
            float v1 = h1v[1] + h2.y;
            float v2 = h1v[2] + h2.z;
            float v3 = h1v[3] + h2.w;
            // leaky-relu in log2 domain; mask score to 0 (exp2(0)=1 -> w=0.25 exact)
            float s0 = on ? fmaxf(v0, 0.2f * v0) : 0.f;
            float s1 = on ? fmaxf(v1, 0.2f * v1) : 0.f;
            float s2 = on ? fmaxf(v2, 0.2f * v2) : 0.f;
            float s3 = on ? fmaxf(v3, 0.2f * v3) : 0.f;
            float e0 = EXP2(s0);
            float e1 = EXP2(s1);
            float e2 = EXP2(s2);
            float e3 = EXP2(s3);
            float zi = __builtin_amdgcn_rcpf(e0 + e1 + e2 + e3);
            af[0][e] = (__bf16)(e0 * zi);
            af[1][e] = (__bf16)(e1 * zi);
            af[2][e] = (__bf16)(e2 * zi);
            af[3][e] = (__bf16)(e3 * zi);
        }

        // ---- MFMA: 4 heads x 4 d-tiles; B-frag = coalesced 1KB load ----
        __builtin_amdgcn_s_setprio(1);
        #pragma unroll
        for (int h = 0; h < H; ++h) {
            #pragma unroll
            for (int nt = 0; nt < 4; ++nt) {
                bf16x8 bfr = __builtin_bit_cast(bf16x8, Hf[(size_t)h * 64 * 256 + s * 256 + nt * 64]);
                acc[h][nt] = __builtin_amdgcn_mfma_f32_16x16x32_bf16(af[h], bfr, acc[h][nt], 0, 0, 0);
            }
        }
        __builtin_amdgcn_s_setprio(0);

        aw = awn;
    }

    // ---- end-of-kernel reduce: each wave dumps bf16 to its LDS slot; sum 4 slots ----
    #pragma unroll
    for (int h = 0; h < H; ++h)
        #pragma unroll
        for (int nt = 0; nt < 4; ++nt)
            #pragma unroll
            for (int r = 0; r < 4; ++r)
                red[wv][(((h * 4 + nt) * 4 + r)) * 64 + l] = f2bf(acc[h][nt][r]);
    __syncthreads();

    unsigned short* chunk = part + (((size_t)jh * B + b) * 128 + it) * CH;
    #pragma unroll
    for (int k = 0; k < CH / 256; ++k) { // 16
        int idx = t + 256 * k;
        float s = bf2f(red[0][idx]) + bf2f(red[1][idx]) + bf2f(red[2][idx]) + bf2f(red[3][idx]);
        chunk[idx] = f2bf(s);
    }
}

// ---------------- Kernel 3: MFMA out-GEMM, no LDS, no barriers ----------------
__global__ __launch_bounds__(256) void k_out(const unsigned short* __restrict__ part,
                                             const unsigned short* __restrict__ WoF,
                                             const float* __restrict__ bo,
                                             float* __restrict__ out) {
    int bid = blockIdx.x;           // ((b*32)+itg)*2 + eh
    int eh  = bid & 1;
    int itg = (bid >> 1) & 31;
    int b   = bid >> 6;
    int t = threadIdx.x;
    int h = t >> 6, l = t & 63;
    int it0 = itg * 4;
    int m = l & 15;                 // A-row within 16-row tile
    int it = it0 + (m >> 2), kg = m & 3;
    int kh = l >> 4;

    const unsigned short* c0 = part + ((size_t)(0 * B + b) * 128 + it) * CH;
    const unsigned short* c1 = part + ((size_t)(1 * B + b) * 128 + it) * CH;
    const us8* wf = (const us8*)WoF;

    f32x4 acc[8] = {};

    #pragma unroll
    for (int ks = 0; ks < 8; ++ks) {
        int k0 = ks * 32 + kh * 8;
        int nt = (k0 >> 4) & 3, r = k0 >> 6, rw0 = k0 & 15;
        int cidx = ((h * 4 + nt) * 4 + r) * 64 + kg * 16 + rw0;
        us8 p0 = *(const us8*)(c0 + cidx);
        us8 p1 = *(const us8*)(c1 + cidx);
        bf16x8 af;
        #pragma unroll
        for (int e = 0; e < 8; ++e) af[e] = (__bf16)(bf2f(p0[e]) + bf2f(p1[e]));

        #pragma unroll
        for (int etl = 0; etl < 8; ++etl) {
            int et = eh * 8 + etl;
            bf16x8 bh = __builtin_bit_cast(bf16x8, wf[(size_t)(et * 8 + ks) * 64 + l]);
            bf16x8 bl = __builtin_bit_cast(bf16x8, wf[8192 + (size_t)(et * 8 + ks) * 64 + l]);
            acc[etl] = __builtin_amdgcn_mfma_f32_16x16x32_bf16(af, bh, acc[etl], 0, 0, 0);
            acc[etl] = __builtin_amdgcn_mfma_f32_16x16x32_bf16(af, bl, acc[etl], 0, 0, 0);
        }
    }

    #pragma unroll
    for (int etl = 0; etl < 8; ++etl) {
        int e = (eh * 8 + etl) * 16 + (l & 15);
        float bias = bo[e];
        #pragma unroll
        for (int rr = 0; rr < 4; ++rr) {
            int nprime = h * 512 + (it0 + (l >> 4)) * 4 + rr;
            out[((size_t)b * N + nprime) * E + e] = acc[etl][rr] + bias;
        }
    }
}

extern "C" void kernel_launch(void* const* d_in, const int* in_sizes, int n_in,
                              void* d_out, int out_size, void* d_ws, size_t ws_size,
                              hipStream_t stream) {
    const float* X  = (const float*)d_in[0];
    const int*   A  = (const int*)d_in[1];
    const float* W  = (const float*)d_in[2];
    const float* a  = (const float*)d_in[3];
    const float* Wo = (const float*)d_in[4];
    const float* bo = (const float*)d_in[5];
    float* out = (float*)d_out;

    // ws: 2 partials (8.4MB), HpF (4.2MB), H1 (128KB), H2i (128KB), Abits (2MB),
    //     WoF (256KB), WfF (256KB)
    unsigned short* wsu  = (unsigned short*)d_ws;
    unsigned short* part = wsu;
    unsigned short* HpF  = wsu + (size_t)2 * B * 128 * CH;
    float* H1  = (float*)(HpF + (size_t)B * H * D * N);
    float* H2i = H1 + B * H * N;
    unsigned int* Abits = (unsigned int*)(H2i + (size_t)B * N * H);
    unsigned short* WoF = (unsigned short*)(Abits + (size_t)B * 64 * 2048);
    unsigned short* WfF = WoF + 2 * 8192 * 8;

    k_wconv<<<dim3(64), dim3(256), 0, stream>>>(Wo, W, WoF, WfF);
    k_prep<<<dim3(PROJ_BLKS + PACK_BLKS), dim3(256), 0, stream>>>(
        X, A, a, WfF, HpF, H1, H2i, Abits);
    k_agg<<<dim3(2 * B * 128), dim3(256), 0, stream>>>(Abits, H1, H2i, HpF, part);
    k_out<<<dim3(B * 32 * 2), dim3(256), 0, stream>>>(part, WoF, bo, out);
}

// Round 19
// 91.398 us; speedup vs baseline: 1.4506x; 1.1573x over previous
//
#include <hip/hip_runtime.h>

// Problem constants (fixed by setup_inputs)
constexpr int B = 4, N = 2048, I = 256, H = 4, D = 64, E = 256; // E = H*D
constexpr float LOG2E = 1.44269504088896340736f;

typedef __bf16 bf16x8 __attribute__((ext_vector_type(8)));
typedef float f32x4 __attribute__((ext_vector_type(4)));
typedef unsigned short us8 __attribute__((ext_vector_type(8)));

#if __has_builtin(__builtin_amdgcn_exp2f)
#define EXP2(x) __builtin_amdgcn_exp2f(x)
#else
#define EXP2(x) __expf((x) * 0.69314718055994530942f)
#endif

__device__ __forceinline__ unsigned short f2bf(float f) {
    unsigned u = __builtin_bit_cast(unsigned, f);
    u = (u + 0x7FFFu + ((u >> 16) & 1u)) >> 16;  // RNE
    return (unsigned short)u;
}
__device__ __forceinline__ float bf2f(unsigned short s) {
    return __builtin_bit_cast(float, (unsigned)s << 16);
}

constexpr int CH = 4096;       // u16 per reduce slot: 64 q-slots x 64 lanes
constexpr int PROJ_BLKS = 256; // 512 row-tiles x 2 eh / 4 waves
constexpr int PACK_BLKS = B * N / 4;

// ---------------- Kernel 0: weight conversions (must precede k_prep/k_agg) ----------------
__global__ __launch_bounds__(256) void k_wconv(const float* __restrict__ Wo,
                                               const float* __restrict__ W,
                                               unsigned short* __restrict__ WoF,
                                               unsigned short* __restrict__ WfF) {
    int bid = blockIdx.x;
    int t = threadIdx.x;
    if (bid < 32) {
        int gid = bid * 256 + t;  // 8192
        int l = gid & 63, ks = (gid >> 6) & 7, et = gid >> 9;
        int row = et * 16 + (l & 15);
        int col = ks * 32 + (l >> 4) * 8;
        const float* src = Wo + (size_t)row * E + col;
        us8 hi, lo;
        #pragma unroll
        for (int e = 0; e < 8; ++e) {
            float v = src[e];
            unsigned short hb = f2bf(v);
            hi[e] = hb;
            lo[e] = f2bf(v - bf2f(hb));
        }
        ((us8*)WoF)[gid] = hi;
        ((us8*)WoF)[8192 + gid] = lo;
    } else {
        int gid = (bid - 32) * 256 + t;  // 8192
        int l = gid & 63, ks = (gid >> 6) & 7, et = gid >> 9;
        int c = et * 16 + (l & 15);
        int h = c >> 6, d = c & 63;
        int k0 = ks * 32 + (l >> 4) * 8;
        const float* src = W + ((size_t)h * I + k0) * D + d; // stride D per k
        us8 hi, lo;
        #pragma unroll
        for (int e = 0; e < 8; ++e) {
            float v = src[(size_t)e * D];
            unsigned short hb = f2bf(v);
            hi[e] = hb;
            lo[e] = f2bf(v - bf2f(hb));
        }
        ((us8*)WfF)[gid] = hi;
        ((us8*)WfF)[8192 + gid] = lo;
    }
}

// ---------------- Kernel 1 (fused prep): MFMA projection | adjacency pack ----------------
// (verified R18 structure, unchanged)
__global__ __launch_bounds__(256) void k_prep(const float* __restrict__ X,
                                              const int* __restrict__ A,
                                              const float* __restrict__ a,
                                              const unsigned short* __restrict__ WfF,
                                              unsigned short* __restrict__ HpF,
                                              float* __restrict__ H1,
                                              float* __restrict__ H2i,
                                              unsigned int* __restrict__ Abits) {
    __shared__ float ldsT[4][16 * 132]; // per-wave transpose scratch, pad stride 132

    int bid = blockIdx.x;
    int t = threadIdx.x;

    if (bid < PROJ_BLKS) {
        int wv = t >> 6, l = t & 63;
        int u = bid * 4 + wv;
        int eh = u & 1;
        int rt = u >> 1;
        int b = rt >> 7;
        int n0 = (rt & 127) * 16;
        int m = l & 15;   // A-frag row
        int kh = l >> 4;  // k-chunk

        const float* Xrow = X + ((size_t)b * N + n0 + m) * I + kh * 8;
        const us8* wf = (const us8*)WfF;

        f32x4 acc[8] = {};

        #pragma unroll
        for (int ks = 0; ks < 8; ++ks) {
            float4 xa = *(const float4*)(Xrow + ks * 32);
            float4 xb = *(const float4*)(Xrow + ks * 32 + 4);
            float xv[8] = {xa.x, xa.y, xa.z, xa.w, xb.x, xb.y, xb.z, xb.w};
            bf16x8 xh, xl;
            #pragma unroll
            for (int e = 0; e < 8; ++e) {
                unsigned short hb = f2bf(xv[e]);
                xh[e] = __builtin_bit_cast(__bf16, hb);
                xl[e] = __builtin_bit_cast(__bf16, f2bf(xv[e] - bf2f(hb)));
            }
            #pragma unroll
            for (int etl = 0; etl < 8; ++etl) {
                int et = eh * 8 + etl;
                bf16x8 wh = __builtin_bit_cast(bf16x8, wf[(size_t)(et * 8 + ks) * 64 + l]);
                bf16x8 wl = __builtin_bit_cast(bf16x8, wf[8192 + (size_t)(et * 8 + ks) * 64 + l]);
                acc[etl] = __builtin_amdgcn_mfma_f32_16x16x32_bf16(xh, wh, acc[etl], 0, 0, 0);
                acc[etl] = __builtin_amdgcn_mfma_f32_16x16x32_bf16(xl, wh, acc[etl], 0, 0, 0);
                acc[etl] = __builtin_amdgcn_mfma_f32_16x16x32_bf16(xh, wl, acc[etl], 0, 0, 0);
            }
        }

        // ---- H1/H2: dot with a over d, reduce over the 16 C-cols ----
        float a1v[8], a2v[8];
        #pragma unroll
        for (int etl = 0; etl < 8; ++etl) {
            int c = eh * 128 + etl * 16 + m; // C col = l&15
            int h = c >> 6, d = c & 63;
            a1v[etl] = a[h * (2 * D) + d];
            a2v[etl] = a[h * (2 * D) + D + d];
        }
        #pragma unroll
        for (int hh = 0; hh < 2; ++hh) {
            #pragma unroll
            for (int r = 0; r < 4; ++r) {
                float s1 = 0.f, s2 = 0.f;
                #pragma unroll
                for (int q = 0; q < 4; ++q) {
                    s1 += acc[hh * 4 + q][r] * a1v[hh * 4 + q];
                    s2 += acc[hh * 4 + q][r] * a2v[hh * 4 + q];
                }
                #pragma unroll
                for (int off = 1; off < 16; off <<= 1) {
                    s1 += __shfl_xor(s1, off, 64);
                    s2 += __shfl_xor(s2, off, 64);
                }
                if (m == 0) {
                    int hg = eh * 2 + hh;
                    int row = kh * 4 + r; // C row
                    H1[(size_t)(b * H + hg) * N + n0 + row] = s1 * LOG2E;
                    H2i[((size_t)b * N + n0 + row) * H + hg] = s2 * LOG2E;
                }
            }
        }

        // ---- HpF: per-wave LDS transpose (same-wave, no barrier needed) ----
        float* lw = ldsT[wv];
        #pragma unroll
        for (int etl = 0; etl < 8; ++etl)
            #pragma unroll
            for (int r = 0; r < 4; ++r)
                lw[(kh * 4 + r) * 132 + etl * 16 + m] = acc[etl][r];

        #pragma unroll
        for (int cc = 0; cc < 4; ++cc) {
            int ci = cc * 64 + l;
            int c_local = ci >> 1, q = ci & 1;
            us8 o;
            #pragma unroll
            for (int e = 0; e < 8; ++e)
                o[e] = f2bf(lw[(q * 8 + e) * 132 + c_local]);
            int cg = eh * 128 + c_local;
            int h = cg >> 6, d = cg & 63;
            int nb = n0 + q * 8;
            int jblk = nb >> 5, g = (nb >> 3) & 3;
            ((us8*)HpF)[(((size_t)(b * H + h) * 64 + jblk) * 4 + (d >> 4)) * 64 + ((d & 15) + 16 * g)] = o;
        }

    } else {
        // ---------------- adjacency pack: coalesced loads + 8-lane shfl-OR ----------------
        int blk = bid - PROJ_BLKS;
        int w = blk * 4 + (t >> 6); // row id = b*N + i
        int l = t & 63;
        int b = w >> 11;
        int i = w & 2047;
        const int4* Arow = (const int4*)(A + (size_t)w * N);
        unsigned int* dstb = Abits + (size_t)b * 64 * 2048 + i; // column-major [b][jw][i]
        #pragma unroll
        for (int c = 0; c < 8; ++c) {
            int4 v = Arow[c * 64 + l]; // coalesced: ints 4*(c*64+l)..+4
            unsigned nib = ((unsigned)v.x | ((unsigned)v.y << 1) |
                            ((unsigned)v.z << 2) | ((unsigned)v.w << 3)) << ((l & 7) * 4);
            nib |= __shfl_xor((int)nib, 1, 64);
            nib |= __shfl_xor((int)nib, 2, 64);
            nib |= __shfl_xor((int)nib, 4, 64);
            if ((l & 7) == 0) dstb[(size_t)(c * 8 + (l >> 3)) * 2048] = nib;
        }
    }
}

// ---------------- Kernel 2 (fused agg+out): softmax-agg over full j + out-GEMM ----------------
// 512 blocks x 8 waves. Block = (b, i-tile); wave wv covers j in [wv*256, +256) —
// per-wave loop body BYTE-IDENTICAL to the verified 49.5us R18 schedule (NSTEP 8,
// unroll-2 mask rotation, setprio around MFMA cluster). XCD-locality: bid&3=b, so
// each XCD (bid%8) sees one b: HpF(b) 1MB + Abits(b) 512KB + H2i(b) = L2-resident.
// Epilogue: 8-slot LDS dump -> thread-local 8-way sum into slot 0 (R in bf16) ->
// each wave computes 2 of 16 et-tiles of out = R @ Wo^T + bias (A-frags via
// ds_read_b128 from slot 0; WoF hi/lo pair keeps Wo fp32-exact). One i-tile = 16
// complete rows of the reshaped R, so the block writes its 16 out rows directly.
constexpr int NSTEP = 8;

__global__ __launch_bounds__(512) void k_agg(const unsigned int* __restrict__ Abits,
                                             const float* __restrict__ H1,
                                             const float* __restrict__ H2i,
                                             const unsigned short* __restrict__ HpF,
                                             const unsigned short* __restrict__ WoF,
                                             const float* __restrict__ bo,
                                             float* __restrict__ out) {
    __shared__ unsigned short red[8][CH]; // 64 KB

    int bid = blockIdx.x;
    int b  = bid & 3;            // low bits -> XCD-locality
    int it = bid >> 2;           // 0..127
    int t = threadIdx.x;
    int wv = t >> 6, l = t & 63; // 8 waves
    int i0 = it * 16;
    int jb = wv * 256;
    int jt0 = wv * 8;            // first 32-j tile index
    int row = l & 15;  // A-frag row / B-frag col
    int kg  = l >> 4;  // k-chunk: k = kg*8 + e

    float h1v[H];
    #pragma unroll
    for (int h = 0; h < H; ++h) h1v[h] = H1[(size_t)(b * H + h) * N + i0 + row];

    f32x4 acc[H][4] = {}; // [head][d-tile]

    const unsigned int* Abp = Abits + (size_t)b * 64 * 2048 + i0 + row; // + jt*2048
    const float4* H2r = (const float4*)(H2i + ((size_t)b * N + jb + kg * 8) * H);
    const us8* Hf = (const us8*)HpF + ((size_t)(b * H) * 64 + jt0) * 256 + l;

    unsigned int aw = Abp[(size_t)jt0 * 2048];

    #pragma unroll 2
    for (int s = 0; s < NSTEP; ++s) {
        int sn = (s + 1 < NSTEP) ? (s + 1) : s;
        unsigned int awn = Abp[(size_t)(jt0 + sn) * 2048];

        // ---- softmax for 8 pairs, all 4 heads; bit-test mask, one float4 H2/pair ----
        bf16x8 af[H];
        #pragma unroll
        for (int e = 0; e < 8; ++e) {
            bool on = (aw >> (kg * 8 + e)) & 1u;
            float4 h2 = H2r[s * 32 + e]; // heads 0..3 of pair j = jb+kg*8+s*32+e
            float v0 = h1v[0] + h2.x;
            float v1 = h1v[1] + h2.y;
            float v2 = h1v[2] + h2.z;
            float v3 = h1v[3] + h2.w;
            // leaky-relu in log2 domain; mask score to 0 (exp2(0)=1 -> w=0.25 exact)
            float s0 = on ? fmaxf(v0, 0.2f * v0) : 0.f;
            float s1 = on ? fmaxf(v1, 0.2f * v1) : 0.f;
            float s2 = on ? fmaxf(v2, 0.2f * v2) : 0.f;
            float s3 = on ? fmaxf(v3, 0.2f * v3) : 0.f;
            float e0 = EXP2(s0);
            float e1 = EXP2(s1);
            float e2 = EXP2(s2);
            float e3 = EXP2(s3);
            float zi = __builtin_amdgcn_rcpf(e0 + e1 + e2 + e3);
            af[0][e] = (__bf16)(e0 * zi);
            af[1][e] = (__bf16)(e1 * zi);
            af[2][e] = (__bf16)(e2 * zi);
            af[3][e] = (__bf16)(e3 * zi);
        }

        // ---- MFMA: 4 heads x 4 d-tiles; B-frag = coalesced 1KB load ----
        __builtin_amdgcn_s_setprio(1);
        #pragma unroll
        for (int h = 0; h < H; ++h) {
            #pragma unroll
            for (int nt = 0; nt < 4; ++nt) {
                bf16x8 bfr = __builtin_bit_cast(bf16x8, Hf[(size_t)h * 64 * 256 + s * 256 + nt * 64]);
                acc[h][nt] = __builtin_amdgcn_mfma_f32_16x16x32_bf16(af[h], bfr, acc[h][nt], 0, 0, 0);
            }
        }
        __builtin_amdgcn_s_setprio(0);

        aw = awn;
    }

    // ---- reduce: every wave dumps bf16 to its slot ----
    #pragma unroll
    for (int h = 0; h < H; ++h)
        #pragma unroll
        for (int nt = 0; nt < 4; ++nt)
            #pragma unroll
            for (int r = 0; r < 4; ++r)
                red[wv][(((h * 4 + nt) * 4 + r)) * 64 + l] = f2bf(acc[h][nt][r]);
    __syncthreads();

    // ---- thread-local 8-slot sum -> slot 0 (R tile in bf16) ----
    {
        int idx8 = t * 8;
        float s8[8] = {0.f, 0.f, 0.f, 0.f, 0.f, 0.f, 0.f, 0.f};
        #pragma unroll
        for (int slot = 0; slot < 8; ++slot) {
            us8 raw = *(const us8*)&red[slot][idx8];
            #pragma unroll
            for (int e = 0; e < 8; ++e) s8[e] += bf2f(raw[e]);
        }
        us8 o;
        #pragma unroll
        for (int e = 0; e < 8; ++e) o[e] = f2bf(s8[e]);
        *(us8*)&red[0][idx8] = o;
    }
    __syncthreads();

    // ---- out-GEMM: 16 rows x 256 cols; wave wv handles et = wv*2, wv*2+1 ----
    // A-frag (row m=l&15 -> h2=m>>2, g=m&3; k=ks*32+(l>>4)*8+e): 16B ds_read from slot0
    // at ridx = ((h2*4+nt2)*4+c)*64 + g*16 + dl, c=k>>6, nt2=(k&63)>>4, dl=k&15 (dl in {0,8}).
    const us8* wf = (const us8*)WoF;
    f32x4 acc2[2] = {};

    #pragma unroll
    for (int ks = 0; ks < 8; ++ks) {
        int kk = ks * 32 + (l >> 4) * 8;
        int c = kk >> 6, d0 = kk & 63;
        int nt2 = d0 >> 4, dl = d0 & 15;
        int h2 = (l & 15) >> 2, g = (l & 15) & 3;
        int ridx = (((h2 * 4 + nt2) * 4 + c) * 64 + g * 16 + dl);
        bf16x8 afr = *(const bf16x8*)&red[0][ridx];

        #pragma unroll
        for (int etl = 0; etl < 2; ++etl) {
            int et = wv * 2 + etl;
            bf16x8 bh = __builtin_bit_cast(bf16x8, wf[(size_t)(et * 8 + ks) * 64 + l]);
            bf16x8 bl = __builtin_bit_cast(bf16x8, wf[8192 + (size_t)(et * 8 + ks) * 64 + l]);
            acc2[etl] = __builtin_amdgcn_mfma_f32_16x16x32_bf16(afr, bh, acc2[etl], 0, 0, 0);
            acc2[etl] = __builtin_amdgcn_mfma_f32_16x16x32_bf16(afr, bl, acc2[etl], 0, 0, 0);
        }
    }

    // epilogue: C col=(l&15) within et-tile, row m'=(l>>4)*4+rr -> n' = (m'>>2)*512 + it*4 + (m'&3)
    #pragma unroll
    for (int etl = 0; etl < 2; ++etl) {
        int e = (wv * 2 + etl) * 16 + (l & 15);
        float bias = bo[e];
        #pragma unroll
        for (int rr = 0; rr < 4; ++rr) {
            int mprime = (l >> 4) * 4 + rr;
            int nprime = (mprime >> 2) * 512 + it * 4 + (mprime & 3);
            out[((size_t)b * N + nprime) * E + e] = acc2[etl][rr] + bias;
        }
    }
}

extern "C" void kernel_launch(void* const* d_in, const int* in_sizes, int n_in,
                              void* d_out, int out_size, void* d_ws, size_t ws_size,
                              hipStream_t stream) {
    const float* X  = (const float*)d_in[0];
    const int*   A  = (const int*)d_in[1];
    const float* W  = (const float*)d_in[2];
    const float* a  = (const float*)d_in[3];
    const float* Wo = (const float*)d_in[4];
    const float* bo = (const float*)d_in[5];
    float* out = (float*)d_out;

    // ws: HpF (4.2MB), H1 (128KB), H2i (128KB), Abits (2MB), WoF (256KB), WfF (256KB)
    unsigned short* wsu = (unsigned short*)d_ws;
    unsigned short* HpF = wsu;
    float* H1  = (float*)(HpF + (size_t)B * H * D * N);
    float* H2i = H1 + B * H * N;
    unsigned int* Abits = (unsigned int*)(H2i + (size_t)B * N * H);
    unsigned short* WoF = (unsigned short*)(Abits + (size_t)B * 64 * 2048);
    unsigned short* WfF = WoF + 2 * 8192 * 8;

    k_wconv<<<dim3(64), dim3(256), 0, stream>>>(Wo, W, WoF, WfF);
    k_prep<<<dim3(PROJ_BLKS + PACK_BLKS), dim3(256), 0, stream>>>(
        X, A, a, WfF, HpF, H1, H2i, Abits);
    k_agg<<<dim3(B * 128), dim3(512), 0, stream>>>(Abits, H1, H2i, HpF, WoF, bo, out);
}